// Round 12
// baseline (713.224 us; speedup 1.0000x reference)
//
#include <hip/hip_runtime.h>

typedef __attribute__((ext_vector_type(8))) short bf16x8;
typedef __attribute__((ext_vector_type(4))) float f32x4;
typedef unsigned short u16;
typedef unsigned int u32;

constexpr int kH   = 2048;   // hidden
constexpr int kI   = 1024;   // intermediate
constexpr int kE   = 32;     // experts
constexpr int kK   = 8;      // experts per token
constexpr int kG   = 8;      // groups
constexpr int kKG  = 4;      // groups kept
constexpr int kCap = 1024;   // capacity
constexpr float kScale = 2.5f;

__device__ __forceinline__ u16 f2bf(float f) {
    union { float f; u32 u; } v; v.f = f;
    u32 u = v.u + 0x7FFFu + ((v.u >> 16) & 1u);  // RNE
    return (u16)(u >> 16);
}
__device__ __forceinline__ float bf2f(u16 b) {
    union { u32 u; float f; } v; v.u = (u32)b << 16; return v.f;
}
__device__ __forceinline__ u32 pk2(float a, float b) {
    return (u32)f2bf(a) | ((u32)f2bf(b) << 16);
}

// ---- 64-elem-row (128B) swizzle ----
__device__ __forceinline__ int swz(int row, int k) {
    return row * 64 + (k ^ ((((row >> 3) ^ row) & 7) << 3));
}
__device__ __forceinline__ int s8(int row) { return ((row >> 3) ^ row) & 7; }

// async global->LDS, 16B per lane; LDS dest wave-uniform (HW adds lane*16B)
__device__ __forceinline__ void gload16(const void* g, void* l) {
    __builtin_amdgcn_global_load_lds(
        (const __attribute__((address_space(1))) unsigned int*)g,
        (__attribute__((address_space(3))) unsigned int*)l, 16, 0, 0);
}

// ---------------- gate: routing + fused x->bf16 convert ----------------
__global__ __launch_bounds__(256) void gate_kernel(
    const float* __restrict__ x, const float* __restrict__ w_gate,
    const float* __restrict__ gbias,
    int* __restrict__ cnt, int* __restrict__ tok_of_slot, float* __restrict__ wt_of_slot,
    int* __restrict__ route_slot, float* __restrict__ route_w, u16* __restrict__ xb)
{
    int tok = blockIdx.x;
    int t = threadIdx.x;
    __shared__ float part[256];
    __shared__ float sc[kE], sb[kE];

    const float* xr = x + (size_t)tok * kH;

    if (xb) {
        const float* p = xr + t * 8;
        float4 a = *(const float4*)p;
        float4 b = *(const float4*)(p + 4);
        uint4 o;
        o.x = pk2(a.x, a.y); o.y = pk2(a.z, a.w);
        o.z = pk2(b.x, b.y); o.w = pk2(b.z, b.w);
        *(uint4*)(xb + (size_t)tok * kH + t * 8) = o;
    }

    int e = t & 31, c = t >> 5;
    const float* wg = w_gate + e;
    float s = 0.f;
    #pragma unroll 4
    for (int h = c * 256; h < c * 256 + 256; ++h)
        s += xr[h] * wg[(size_t)h * kE];
    part[t] = s;
    __syncthreads();

    if (t < kE) {
        float logit = 0.f;
        #pragma unroll
        for (int cc = 0; cc < 8; ++cc) logit += part[t + 32 * cc];
        float sco = 1.f / (1.f + expf(-logit));
        sc[t] = sco;
        sb[t] = sco + gbias[t];
    }
    __syncthreads();

    if (t == 0) {
        float gsc[kG];
        for (int g = 0; g < kG; ++g) {
            float m1 = -1e30f, m2 = -1e30f;
            for (int j = 0; j < 4; ++j) {
                float v = sb[g * 4 + j];
                if (v > m1) { m2 = m1; m1 = v; } else if (v > m2) { m2 = v; }
            }
            gsc[g] = m1 + m2;
        }
        bool gkeep[kG];
        for (int g = 0; g < kG; ++g) gkeep[g] = false;
        for (int it = 0; it < kKG; ++it) {
            float best = -1e30f; int bi = 0;
            for (int g = 0; g < kG; ++g)
                if (!gkeep[g] && gsc[g] > best) { best = gsc[g]; bi = g; }
            gkeep[bi] = true;
        }
        bool taken[kE];
        for (int i = 0; i < kE; ++i) taken[i] = false;
        int sel[kK]; float selw[kK]; float wsum = 0.f;
        for (int it = 0; it < kK; ++it) {
            float best = -1e30f; int bi = 0;
            for (int i = 0; i < kE; ++i)
                if (gkeep[i >> 2] && !taken[i] && sb[i] > best) { best = sb[i]; bi = i; }
            taken[bi] = true;
            sel[it] = bi; selw[it] = sc[bi]; wsum += sc[bi];
        }
        float scl = kScale / wsum;
        for (int it = 0; it < kK; ++it) {
            int ee = sel[it];
            int slot = atomicAdd(&cnt[ee], 1);
            if (slot < kCap) {
                tok_of_slot[ee * kCap + slot] = tok;
                wt_of_slot[ee * kCap + slot] = selw[it] * scl;
                route_slot[tok * kK + it] = ee * kCap + slot;
                route_w[tok * kK + it]   = selw[it] * scl;
            } else {
                route_slot[tok * kK + it] = -1;
                route_w[tok * kK + it]   = 0.f;
            }
        }
    }
}

// ---------------- prep_w: [R][C] fp32 -> [C][R] bf16 ----------------
// 4096 blocks x 6 tiles, cross-tile register double-buffer: tile i+1's strided
// loads issue before tile i's LDS/store phases (latency hides under LDS work,
// blocks live 6x longer -> no dispatch churn).
__global__ __launch_bounds__(256) void prep_w_kernel(
    const float* __restrict__ w1, const float* __restrict__ w3, const float* __restrict__ w2,
    u16* __restrict__ w1t, u16* __restrict__ w3t, u16* __restrict__ w2t)
{
    __shared__ u16 Tl[2][4104];
    int b = blockIdx.x;          // 4096 blocks, 6 consecutive tiles each
    int t = threadIdx.x;
    int bn = (t & 15) * 4, bk = (t >> 4) * 4;

    auto decode = [&](int gid, const float*& se, u16*& de, int& R, int& C, int& n0, int& k0) {
        int group = gid >> 8;    // 0..95 = (e, ty)
        int tile  = gid & 255;
        int ty = group % 3;
        int e  = group / 3;
        R = (ty == 2) ? kI : kH;
        C = (ty == 2) ? kH : kI;
        const float* s = (ty == 0) ? w1 : (ty == 1) ? w3 : w2;
        u16* d = (ty == 0) ? w1t : (ty == 1) ? w3t : w2t;
        se = s + (size_t)e * R * C;
        de = d + (size_t)e * R * C;
        int cl = (ty == 2) ? 5 : 4;              // log2(C/64)
        n0 = (tile & ((1 << cl) - 1)) << 6;
        k0 = (tile >> cl) << 7;
    };

    const float* se; u16* de; int R, C, n0, k0;
    float4 cur[8], nxt[8];

    decode(b * 6, se, de, R, C, n0, k0);
    #pragma unroll
    for (int sub = 0; sub < 2; ++sub)
        #pragma unroll
        for (int rr = 0; rr < 4; ++rr)
            cur[sub * 4 + rr] =
                *(const float4*)(se + (size_t)(k0 + sub * 64 + bk + rr) * C + n0 + bn);

    const float* se2 = se; u16* de2 = de; int R2 = R, C2 = C, n02 = n0, k02 = k0;

    for (int i = 0; i < 6; ++i) {
        if (i < 5) {
            decode(b * 6 + i + 1, se2, de2, R2, C2, n02, k02);
            #pragma unroll
            for (int sub = 0; sub < 2; ++sub)
                #pragma unroll
                for (int rr = 0; rr < 4; ++rr)
                    nxt[sub * 4 + rr] =
                        *(const float4*)(se2 + (size_t)(k02 + sub * 64 + bk + rr) * C2 + n02 + bn);
        }
        if (i) __syncthreads();      // LDS free from previous read phase
        #pragma unroll
        for (int sub = 0; sub < 2; ++sub) {
            u16* T = Tl[sub];
            float4 c0 = cur[sub * 4 + 0], c1 = cur[sub * 4 + 1];
            float4 c2 = cur[sub * 4 + 2], c3 = cur[sub * 4 + 3];
            uint2 q;
            q.x = pk2(c0.x, c1.x); q.y = pk2(c2.x, c3.x); *(uint2*)&T[swz(bn + 0, bk)] = q;
            q.x = pk2(c0.y, c1.y); q.y = pk2(c2.y, c3.y); *(uint2*)&T[swz(bn + 1, bk)] = q;
            q.x = pk2(c0.z, c1.z); q.y = pk2(c2.z, c3.z); *(uint2*)&T[swz(bn + 2, bk)] = q;
            q.x = pk2(c0.w, c1.w); q.y = pk2(c2.w, c3.w); *(uint2*)&T[swz(bn + 3, bk)] = q;
        }
        __syncthreads();
        #pragma unroll
        for (int it = 0; it < 4; ++it) {
            int f = it * 256 + t;
            int n = f >> 4, cc = f & 15;
            int sub = cc >> 3, kk = (cc & 7) * 8;
            uint4 v = *(const uint4*)&Tl[sub][swz(n, kk)];
            *(uint4*)(de + (size_t)(n0 + n) * R + k0 + sub * 64 + kk) = v;
        }
        se = se2; de = de2; R = R2; C = C2; n0 = n02; k0 = k02;
        #pragma unroll
        for (int j = 0; j < 8; ++j) cur[j] = nxt[j];
    }
}

// ---------------- GEMM1: act = silu(xb@w1t^T)*(xb@w3t^T); R5 dbuf + XCD swizzle ----------------
__global__ __launch_bounds__(256, 2) void gemm1_kernel(
    const u16* __restrict__ xb, const u16* __restrict__ w1t, const u16* __restrict__ w3t,
    const int* __restrict__ tok_of_slot, const int* __restrict__ cnt,
    u16* __restrict__ act)
{
    int orig = blockIdx.x;
    int wg = (orig & 7) * 512 + (orig >> 3);
    int e = wg >> 7;
    int r = wg & 127;
    int m0 = (r >> 4) * 128;   // m-outer
    int n0 = (r & 15) * 64;    // n-inner

    int count = cnt[e];
    if (m0 >= count) return;

    __shared__ u16 sh[2][16384];

    int t = threadIdx.x;
    int oct = t & 7;
    int wb = (t >> 6) * 512;

    const u16* srcA[4];
    #pragma unroll
    for (int rr = 0; rr < 4; ++rr) {
        int row = rr * 32 + (t >> 3);
        int grow = m0 + row;
        int tk = (grow < count) ? tok_of_slot[e * kCap + grow] : 0;
        tk = (tk >= 0 && tk < 65536) ? tk : 0;
        srcA[rr] = xb + (size_t)tk * kH + ((oct ^ s8(row)) << 3);
    }
    const u16 *srcB1[2], *srcB3[2];
    #pragma unroll
    for (int rr = 0; rr < 2; ++rr) {
        int row = rr * 32 + (t >> 3);
        size_t go = (size_t)(n0 + row) * kH + ((oct ^ s8(row)) << 3);
        srcB1[rr] = w1t + (size_t)e * kH * kI + go;
        srcB3[rr] = w3t + (size_t)e * kH * kI + go;
    }

    auto stage = [&](int b, int k0) {
        u16* D = sh[b];
        #pragma unroll
        for (int rr = 0; rr < 4; ++rr)
            gload16(srcA[rr] + k0, D + rr * 2048 + wb);
        #pragma unroll
        for (int rr = 0; rr < 2; ++rr) {
            gload16(srcB1[rr] + k0, D + 8192 + rr * 2048 + wb);
            gload16(srcB3[rr] + k0, D + 12288 + rr * 2048 + wb);
        }
    };

    int lane = t & 63;
    int wv = t >> 6;
    int wm = (wv >> 1) * 64;
    int wn = (wv & 1) * 32;
    int lr = lane & 15;
    int kg = lane >> 4;

    f32x4 accg[4][2], accu[4][2];
    #pragma unroll
    for (int i = 0; i < 4; ++i)
        #pragma unroll
        for (int j = 0; j < 2; ++j) {
            accg[i][j] = f32x4{0.f, 0.f, 0.f, 0.f};
            accu[i][j] = f32x4{0.f, 0.f, 0.f, 0.f};
        }

    stage(0, 0);
    __syncthreads();
    int buf = 0;
    constexpr int NT = kH / 64;
    for (int kt = 0; kt < NT; ++kt) {
        if (kt + 1 < NT) stage(buf ^ 1, (kt + 1) * 64);
        const u16* As  = &sh[buf][0];
        const u16* B1s = &sh[buf][8192];
        const u16* B3s = &sh[buf][12288];
        #pragma unroll
        for (int h = 0; h < 2; ++h) {
            int kk = h * 32 + kg * 8;
            bf16x8 a[4];
            #pragma unroll
            for (int i = 0; i < 4; ++i)
                a[i] = *(const bf16x8*)&As[swz(wm + i * 16 + lr, kk)];
            #pragma unroll
            for (int ni = 0; ni < 2; ++ni) {
                bf16x8 b1 = *(const bf16x8*)&B1s[swz(wn + ni * 16 + lr, kk)];
                bf16x8 b3 = *(const bf16x8*)&B3s[swz(wn + ni * 16 + lr, kk)];
                #pragma unroll
                for (int mi = 0; mi < 4; ++mi) {
                    accg[mi][ni] = __builtin_amdgcn_mfma_f32_16x16x32_bf16(a[mi], b1, accg[mi][ni], 0, 0, 0);
                    accu[mi][ni] = __builtin_amdgcn_mfma_f32_16x16x32_bf16(a[mi], b3, accu[mi][ni], 0, 0, 0);
                }
            }
        }
        __syncthreads();
        buf ^= 1;
    }

    u16* actp = act + (size_t)e * kCap * kI;
    #pragma unroll
    for (int mi = 0; mi < 4; ++mi)
        #pragma unroll
        for (int ni = 0; ni < 2; ++ni)
            #pragma unroll
            for (int j = 0; j < 4; ++j) {
                int srow = m0 + wm + mi * 16 + kg * 4 + j;
                int icol = n0 + wn + ni * 16 + lr;
                float g = accg[mi][ni][j], u = accu[mi][ni][j];
                float sg = g / (1.f + __expf(-g));
                actp[(size_t)srow * kI + icol] = f2bf(sg * u);
            }
}

// ---------------- GEMM2: y = act @ w2t^T (bf16 y, no atomics); R5 dbuf + XCD swizzle ----------------
__global__ __launch_bounds__(256, 2) void gemm2_kernel(
    const u16* __restrict__ act, const u16* __restrict__ w2t,
    const int* __restrict__ cnt, u16* __restrict__ y)
{
    int orig = blockIdx.x;
    int wg = (orig & 7) * 512 + (orig >> 3);
    int e = wg >> 7;
    int r = wg & 127;
    int m0 = (r >> 4) * 128;   // m-outer
    int n0 = (r & 15) * 128;   // n-inner

    int count = cnt[e];
    if (m0 >= count) return;

    __shared__ u16 sh[2][16384];

    int t = threadIdx.x;
    int oct = t & 7;
    int wb = (t >> 6) * 512;

    const u16* srcA[4];
    const u16* srcB[4];
    {
        const u16* ae  = act + (size_t)e * kCap * kI;
        const u16* w2e = w2t + (size_t)e * kI * kH;
        #pragma unroll
        for (int rr = 0; rr < 4; ++rr) {
            int row = rr * 32 + (t >> 3);
            srcA[rr] = ae  + (size_t)(m0 + row) * kI + ((oct ^ s8(row)) << 3);
            srcB[rr] = w2e + (size_t)(n0 + row) * kI + ((oct ^ s8(row)) << 3);
        }
    }

    auto stage = [&](int b, int k0) {
        u16* D = sh[b];
        #pragma unroll
        for (int rr = 0; rr < 4; ++rr) {
            gload16(srcA[rr] + k0, D + rr * 2048 + wb);
            gload16(srcB[rr] + k0, D + 8192 + rr * 2048 + wb);
        }
    };

    int lane = t & 63;
    int wv = t >> 6;
    int wm = (wv >> 1) * 64;
    int wn = (wv & 1) * 64;
    int lr = lane & 15;
    int kg = lane >> 4;

    f32x4 acc[4][4];
    #pragma unroll
    for (int i = 0; i < 4; ++i)
        #pragma unroll
        for (int j = 0; j < 4; ++j) acc[i][j] = f32x4{0.f, 0.f, 0.f, 0.f};

    stage(0, 0);
    __syncthreads();
    int buf = 0;
    constexpr int NT = kI / 64;
    for (int kt = 0; kt < NT; ++kt) {
        if (kt + 1 < NT) stage(buf ^ 1, (kt + 1) * 64);
        const u16* As = &sh[buf][0];
        const u16* Bs = &sh[buf][8192];
        #pragma unroll
        for (int h = 0; h < 2; ++h) {
            int kk = h * 32 + kg * 8;
            bf16x8 a[4];
            #pragma unroll
            for (int i = 0; i < 4; ++i)
                a[i] = *(const bf16x8*)&As[swz(wm + i * 16 + lr, kk)];
            #pragma unroll
            for (int ni = 0; ni < 4; ++ni) {
                bf16x8 b = *(const bf16x8*)&Bs[swz(wn + ni * 16 + lr, kk)];
                #pragma unroll
                for (int mi = 0; mi < 4; ++mi)
                    acc[mi][ni] = __builtin_amdgcn_mfma_f32_16x16x32_bf16(a[mi], b, acc[mi][ni], 0, 0, 0);
            }
        }
        __syncthreads();
        buf ^= 1;
    }

    u16* ye = y + (size_t)e * kCap * kH;
    #pragma unroll
    for (int mi = 0; mi < 4; ++mi)
        #pragma unroll
        for (int j = 0; j < 4; ++j) {
            int sr = wm + mi * 16 + kg * 4 + j;
            if (m0 + sr < count) {
                #pragma unroll
                for (int ni = 0; ni < 4; ++ni)
                    ye[(size_t)(m0 + sr) * kH + n0 + wn + ni * 16 + lr] = f2bf(acc[mi][ni][j]);
            }
        }
}

// ---------------- combine: out[tok] = sum_k route_w * y[route_slot] ----------------
__global__ __launch_bounds__(256) void combine_kernel(
    const u16* __restrict__ y, const int* __restrict__ route_slot,
    const float* __restrict__ route_w, float* __restrict__ out)
{
    int tok = blockIdx.x;
    int t = threadIdx.x;
    int col = t * 8;

    int rs[kK]; float rw[kK];
    #pragma unroll
    for (int k = 0; k < kK; ++k) {
        rs[k] = route_slot[tok * kK + k];
        rw[k] = route_w[tok * kK + k];
    }

    float acc[8];
    #pragma unroll
    for (int j = 0; j < 8; ++j) acc[j] = 0.f;

    #pragma unroll
    for (int k = 0; k < kK; ++k) {
        if (rs[k] < 0) continue;
        uint4 v = *(const uint4*)(y + (size_t)rs[k] * kH + col);
        const u16* h = (const u16*)&v;
        float w = rw[k];
        #pragma unroll
        for (int j = 0; j < 8; ++j) acc[j] += w * bf2f(h[j]);
    }
    float4 o0 = make_float4(acc[0], acc[1], acc[2], acc[3]);
    float4 o1 = make_float4(acc[4], acc[5], acc[6], acc[7]);
    *(float4*)(out + (size_t)tok * kH + col) = o0;
    *(float4*)(out + (size_t)tok * kH + col + 4) = o1;
}

// ================= legacy fp32-staging kernels (fallback if ws too small) =================
__global__ __launch_bounds__(256, 3) void gemm1_legacy(
    const float* __restrict__ x, const float* __restrict__ w1g, const float* __restrict__ w3g,
    const int* __restrict__ tok_of_slot, const int* __restrict__ cnt,
    u16* __restrict__ act)
{
    int e = blockIdx.z;
    int count = cnt[e];
    int m0 = blockIdx.y * 128;
    if (m0 >= count) return;
    int n0 = blockIdx.x * 64;

    __shared__ u16 As[128 * 64];
    __shared__ u16 B1s[64 * 64];
    __shared__ u16 B3s[64 * 64];
    __shared__ int toks[128];

    int t = threadIdx.x;
    if (t < 128) {
        int s = m0 + t;
        toks[t] = (s < count) ? tok_of_slot[e * kCap + s] : -1;
    }
    __syncthreads();
    int lane = t & 63, wv = t >> 6;
    int wm = (wv >> 1) * 64, wn = (wv & 1) * 32;
    int lr = lane & 15, kg = lane >> 4;

    f32x4 accg[4][2], accu[4][2];
    #pragma unroll
    for (int i = 0; i < 4; ++i)
        #pragma unroll
        for (int j = 0; j < 2; ++j) {
            accg[i][j] = f32x4{0.f, 0.f, 0.f, 0.f};
            accu[i][j] = f32x4{0.f, 0.f, 0.f, 0.f};
        }
    const float* w1e = w1g + (size_t)e * kH * kI;
    const float* w3e = w3g + (size_t)e * kH * kI;

    for (int k0 = 0; k0 < kH; k0 += 64) {
        __syncthreads();
        #pragma unroll
        for (int r = 0; r < 4; ++r) {
            int f = r * 256 + t;
            int row = f >> 3, k8 = (f & 7) * 8;
            int tk = toks[row];
            float4 v0 = make_float4(0.f, 0.f, 0.f, 0.f), v1 = v0;
            if (tk >= 0) {
                const float* p = x + (size_t)tk * kH + k0 + k8;
                v0 = *(const float4*)p; v1 = *(const float4*)(p + 4);
            }
            uint4 w;
            w.x = pk2(v0.x, v0.y); w.y = pk2(v0.z, v0.w);
            w.z = pk2(v1.x, v1.y); w.w = pk2(v1.z, v1.w);
            *(uint4*)&As[swz(row, k8)] = w;
        }
        {
            int bn = (t & 15) * 4, bk = (t >> 4) * 4;
            const float* p1 = w1e + (size_t)(k0 + bk) * kI + n0 + bn;
            float4 c0 = *(const float4*)p1, c1 = *(const float4*)(p1 + kI),
                   c2 = *(const float4*)(p1 + 2 * kI), c3 = *(const float4*)(p1 + 3 * kI);
            uint2 q;
            q.x = pk2(c0.x, c1.x); q.y = pk2(c2.x, c3.x); *(uint2*)&B1s[swz(bn + 0, bk)] = q;
            q.x = pk2(c0.y, c1.y); q.y = pk2(c2.y, c3.y); *(uint2*)&B1s[swz(bn + 1, bk)] = q;
            q.x = pk2(c0.z, c1.z); q.y = pk2(c2.z, c3.z); *(uint2*)&B1s[swz(bn + 2, bk)] = q;
            q.x = pk2(c0.w, c1.w); q.y = pk2(c2.w, c3.w); *(uint2*)&B1s[swz(bn + 3, bk)] = q;
            const float* p3 = w3e + (size_t)(k0 + bk) * kI + n0 + bn;
            c0 = *(const float4*)p3; c1 = *(const float4*)(p3 + kI);
            c2 = *(const float4*)(p3 + 2 * kI); c3 = *(const float4*)(p3 + 3 * kI);
            q.x = pk2(c0.x, c1.x); q.y = pk2(c2.x, c3.x); *(uint2*)&B3s[swz(bn + 0, bk)] = q;
            q.x = pk2(c0.y, c1.y); q.y = pk2(c2.y, c3.y); *(uint2*)&B3s[swz(bn + 1, bk)] = q;
            q.x = pk2(c0.z, c1.z); q.y = pk2(c2.z, c3.z); *(uint2*)&B3s[swz(bn + 2, bk)] = q;
            q.x = pk2(c0.w, c1.w); q.y = pk2(c2.w, c3.w); *(uint2*)&B3s[swz(bn + 3, bk)] = q;
        }
        __syncthreads();
        #pragma unroll
        for (int h = 0; h < 2; ++h) {
            int kk = h * 32 + kg * 8;
            bf16x8 a[4];
            #pragma unroll
            for (int i = 0; i < 4; ++i)
                a[i] = *(const bf16x8*)&As[swz(wm + i * 16 + lr, kk)];
            #pragma unroll
            for (int ni = 0; ni < 2; ++ni) {
                bf16x8 b1 = *(const bf16x8*)&B1s[swz(wn + ni * 16 + lr, kk)];
                bf16x8 b3 = *(const bf16x8*)&B3s[swz(wn + ni * 16 + lr, kk)];
                #pragma unroll
                for (int mi = 0; mi < 4; ++mi) {
                    accg[mi][ni] = __builtin_amdgcn_mfma_f32_16x16x32_bf16(a[mi], b1, accg[mi][ni], 0, 0, 0);
                    accu[mi][ni] = __builtin_amdgcn_mfma_f32_16x16x32_bf16(a[mi], b3, accu[mi][ni], 0, 0, 0);
                }
            }
        }
    }
    u16* actp = act + (size_t)e * kCap * kI;
    #pragma unroll
    for (int mi = 0; mi < 4; ++mi)
        #pragma unroll
        for (int ni = 0; ni < 2; ++ni)
            #pragma unroll
            for (int j = 0; j < 4; ++j) {
                int srow = m0 + wm + mi * 16 + kg * 4 + j;
                int icol = n0 + wn + ni * 16 + lr;
                float g = accg[mi][ni][j], u = accu[mi][ni][j];
                float sg = g / (1.f + __expf(-g));
                actp[(size_t)srow * kI + icol] = f2bf(sg * u);
            }
}

__global__ __launch_bounds__(256, 3) void gemm2_legacy(
    const u16* __restrict__ act, const float* __restrict__ w2g,
    const int* __restrict__ tok_of_slot, const float* __restrict__ wt_of_slot,
    const int* __restrict__ cnt, float* __restrict__ out)
{
    int e = blockIdx.z;
    int count = cnt[e];
    int m0 = blockIdx.y * 128;
    if (m0 >= count) return;
    int n0 = blockIdx.x * 128;

    __shared__ u16 As[128 * 64];
    __shared__ u16 Bs[128 * 64];
    __shared__ int toks[128];
    __shared__ float wts[128];

    int t = threadIdx.x;
    if (t < 128) {
        int s = m0 + t;
        toks[t] = (s < count) ? tok_of_slot[e * kCap + s] : 0;
        wts[t]  = (s < count) ? wt_of_slot[e * kCap + s] : 0.f;
    }
    __syncthreads();
    int lane = t & 63, wv = t >> 6;
    int wm = (wv >> 1) * 64, wn = (wv & 1) * 64;
    int lr = lane & 15, kg = lane >> 4;

    f32x4 acc[4][4];
    #pragma unroll
    for (int i = 0; i < 4; ++i)
        #pragma unroll
        for (int j = 0; j < 4; ++j) acc[i][j] = f32x4{0.f, 0.f, 0.f, 0.f};

    const u16* ae = act + (size_t)e * kCap * kI;
    const float* w2e = w2g + (size_t)e * kI * kH;

    for (int k0 = 0; k0 < kI; k0 += 64) {
        __syncthreads();
        #pragma unroll
        for (int r = 0; r < 4; ++r) {
            int f = r * 256 + t;
            int row = f >> 3, k8 = (f & 7) * 8;
            uint4 v = *(const uint4*)(ae + (size_t)(m0 + row) * kI + k0 + k8);
            *(uint4*)&As[swz(row, k8)] = v;
        }
        #pragma unroll
        for (int r = 0; r < 2; ++r) {
            int f = r * 256 + t;
            int bn = (f & 31) * 4, bk = (f >> 5) * 4;
            const float* p = w2e + (size_t)(k0 + bk) * kH + n0 + bn;
            float4 c0 = *(const float4*)p, c1 = *(const float4*)(p + kH),
                   c2 = *(const float4*)(p + 2 * kH), c3 = *(const float4*)(p + 3 * kH);
            uint2 q;
            q.x = pk2(c0.x, c1.x); q.y = pk2(c2.x, c3.x); *(uint2*)&Bs[swz(bn + 0, bk)] = q;
            q.x = pk2(c0.y, c1.y); q.y = pk2(c2.y, c3.y); *(uint2*)&Bs[swz(bn + 1, bk)] = q;
            q.x = pk2(c0.z, c1.z); q.y = pk2(c2.z, c3.z); *(uint2*)&Bs[swz(bn + 2, bk)] = q;
            q.x = pk2(c0.w, c1.w); q.y = pk2(c2.w, c3.w); *(uint2*)&Bs[swz(bn + 3, bk)] = q;
        }
        __syncthreads();
        #pragma unroll
        for (int h = 0; h < 2; ++h) {
            int kk = h * 32 + kg * 8;
            bf16x8 a[4];
            #pragma unroll
            for (int i = 0; i < 4; ++i)
                a[i] = *(const bf16x8*)&As[swz(wm + i * 16 + lr, kk)];
            #pragma unroll
            for (int ni = 0; ni < 4; ++ni) {
                bf16x8 b = *(const bf16x8*)&Bs[swz(wn + ni * 16 + lr, kk)];
                #pragma unroll
                for (int mi = 0; mi < 4; ++mi)
                    acc[mi][ni] = __builtin_amdgcn_mfma_f32_16x16x32_bf16(a[mi], b, acc[mi][ni], 0, 0, 0);
            }
        }
    }
    #pragma unroll
    for (int mi = 0; mi < 4; ++mi)
        #pragma unroll
        for (int ni = 0; ni < 4; ++ni)
            #pragma unroll
            for (int j = 0; j < 4; ++j) {
                int sr = wm + mi * 16 + kg * 4 + j;
                if (m0 + sr < count) {
                    atomicAdd(&out[(size_t)toks[sr] * kH + n0 + wn + ni * 16 + lr],
                              wts[sr] * acc[mi][ni][j]);
                }
            }
}

extern "C" void kernel_launch(void* const* d_in, const int* in_sizes, int n_in,
                              void* d_out, int out_size, void* d_ws, size_t ws_size,
                              hipStream_t stream) {
    const float* x      = (const float*)d_in[0];
    const float* w_gate = (const float*)d_in[1];
    const float* gbias  = (const float*)d_in[2];
    const float* w1     = (const float*)d_in[3];
    const float* w3     = (const float*)d_in[4];
    const float* w2     = (const float*)d_in[5];
    float* out = (float*)d_out;

    int ntok = in_sizes[0] / kH;

    char* ws = (char*)d_ws;
    size_t off = 0;
    int*   cnt         = (int*)(ws + off);   off += 4096;
    int*   tok_of_slot = (int*)(ws + off);   off += (size_t)kE * kCap * 4;
    float* wt_of_slot  = (float*)(ws + off); off += (size_t)kE * kCap * 4;
    int*   route_slot  = (int*)(ws + off);   off += (size_t)ntok * kK * 4;
    float* route_w     = (float*)(ws + off); off += (size_t)ntok * kK * 4;
    u16*   act         = (u16*)(ws + off);   off += (size_t)kE * kCap * kI * 2;  // 64 MB
    u16*   xb  = (u16*)(ws + off); off += (size_t)ntok * kH * 2;                 // 8 MB
    u16*   w1t = (u16*)(ws + off); off += (size_t)kE * kH * kI * 2;              // 128 MB
    u16*   w3t = (u16*)(ws + off); off += (size_t)kE * kH * kI * 2;              // 128 MB
    u16*   w2t = (u16*)(ws + off); off += (size_t)kE * kI * kH * 2;              // 128 MB
    u16*   y   = w1t;   // y[E][kCap][kH] bf16 = 128 MB, aliases w1t (dead after gemm1)

    bool fast = (ws_size >= off);

    hipMemsetAsync(cnt, 0, kE * sizeof(int), stream);

    gate_kernel<<<ntok, 256, 0, stream>>>(x, w_gate, gbias, cnt, tok_of_slot, wt_of_slot,
                                          route_slot, route_w, fast ? xb : nullptr);

    if (fast) {
        prep_w_kernel<<<4096, 256, 0, stream>>>(w1, w3, w2, w1t, w3t, w2t);
        gemm1_kernel<<<4096, 256, 0, stream>>>(xb, w1t, w3t, tok_of_slot, cnt, act);
        gemm2_kernel<<<4096, 256, 0, stream>>>(act, w2t, cnt, y);
        combine_kernel<<<ntok, 256, 0, stream>>>(y, route_slot, route_w, out);
    } else {
        hipMemsetAsync(d_out, 0, (size_t)out_size * sizeof(float), stream);
        dim3 g1(kI / 64, kCap / 128, kE);
        gemm1_legacy<<<g1, 256, 0, stream>>>(x, w1, w3, tok_of_slot, cnt, act);
        dim3 g2(kH / 128, kCap / 128, kE);
        gemm2_legacy<<<g2, 256, 0, stream>>>(act, w2, tok_of_slot, wt_of_slot, cnt, out);
    }
}

// Round 13
// 629.064 us; speedup vs baseline: 1.1338x; 1.1338x over previous
//
#include <hip/hip_runtime.h>

typedef __attribute__((ext_vector_type(8))) short bf16x8;
typedef __attribute__((ext_vector_type(4))) float f32x4;
typedef unsigned short u16;
typedef unsigned int u32;

constexpr int kH   = 2048;   // hidden
constexpr int kI   = 1024;   // intermediate
constexpr int kE   = 32;     // experts
constexpr int kK   = 8;      // experts per token
constexpr int kG   = 8;      // groups
constexpr int kKG  = 4;      // groups kept
constexpr int kCap = 1024;   // capacity
constexpr float kScale = 2.5f;
constexpr int kPrepBlocks = 24576;   // 96 (e,ty) groups x 256 tiles

__device__ __forceinline__ u16 f2bf(float f) {
    union { float f; u32 u; } v; v.f = f;
    u32 u = v.u + 0x7FFFu + ((v.u >> 16) & 1u);  // RNE
    return (u16)(u >> 16);
}
__device__ __forceinline__ float bf2f(u16 b) {
    union { u32 u; float f; } v; v.u = (u32)b << 16; return v.f;
}
__device__ __forceinline__ u32 pk2(float a, float b) {
    return (u32)f2bf(a) | ((u32)f2bf(b) << 16);
}

// ---- 64-elem-row (128B) swizzle ----
__device__ __forceinline__ int swz(int row, int k) {
    return row * 64 + (k ^ ((((row >> 3) ^ row) & 7) << 3));
}
__device__ __forceinline__ int s8(int row) { return ((row >> 3) ^ row) & 7; }

// async global->LDS, 16B per lane; LDS dest wave-uniform (HW adds lane*16B)
__device__ __forceinline__ void gload16(const void* g, void* l) {
    __builtin_amdgcn_global_load_lds(
        (const __attribute__((address_space(1))) unsigned int*)g,
        (__attribute__((address_space(3))) unsigned int*)l, 16, 0, 0);
}

// ---------------- fused prep_gate: gate blocks [0,ntok) + prep_w blocks [ntok,..) ----------------
// gate is latency-bound and independent of prep_w -> its 2048 tiny blocks hide
// entirely under prep_w's memory-bound wave (no-event overlap inside one launch).
__global__ __launch_bounds__(256) void prep_gate_kernel(
    const float* __restrict__ x, const float* __restrict__ w_gate,
    const float* __restrict__ gbias,
    int* __restrict__ cnt, int* __restrict__ tok_of_slot, float* __restrict__ wt_of_slot,
    int* __restrict__ route_slot, float* __restrict__ route_w, u16* __restrict__ xb,
    const float* __restrict__ w1, const float* __restrict__ w3, const float* __restrict__ w2,
    u16* __restrict__ w1t, u16* __restrict__ w3t, u16* __restrict__ w2t, int ntok)
{
    __shared__ __align__(16) char smem[2 * 4104 * 2];   // 16.4 KB union
    int t = threadIdx.x;

    if ((int)blockIdx.x < ntok) {
        // ================= gate path =================
        float* part = (float*)smem;          // 256 floats
        float* sc   = part + 256;            // 32
        float* sb   = sc + 32;               // 32
        int tok = blockIdx.x;
        const float* xr = x + (size_t)tok * kH;

        if (xb) {   // fused x -> bf16
            const float* p = xr + t * 8;
            float4 a = *(const float4*)p;
            float4 b = *(const float4*)(p + 4);
            uint4 o;
            o.x = pk2(a.x, a.y); o.y = pk2(a.z, a.w);
            o.z = pk2(b.x, b.y); o.w = pk2(b.z, b.w);
            *(uint4*)(xb + (size_t)tok * kH + t * 8) = o;
        }

        int e = t & 31, c = t >> 5;
        const float* wg = w_gate + e;
        float s = 0.f;
        #pragma unroll 4
        for (int h = c * 256; h < c * 256 + 256; ++h)
            s += xr[h] * wg[(size_t)h * kE];
        part[t] = s;
        __syncthreads();

        if (t < kE) {
            float logit = 0.f;
            #pragma unroll
            for (int cc = 0; cc < 8; ++cc) logit += part[t + 32 * cc];
            float sco = 1.f / (1.f + expf(-logit));
            sc[t] = sco;
            sb[t] = sco + gbias[t];
        }
        __syncthreads();

        if (t == 0) {
            float gsc[kG];
            for (int g = 0; g < kG; ++g) {
                float m1 = -1e30f, m2 = -1e30f;
                for (int j = 0; j < 4; ++j) {
                    float v = sb[g * 4 + j];
                    if (v > m1) { m2 = m1; m1 = v; } else if (v > m2) { m2 = v; }
                }
                gsc[g] = m1 + m2;
            }
            bool gkeep[kG];
            for (int g = 0; g < kG; ++g) gkeep[g] = false;
            for (int it = 0; it < kKG; ++it) {
                float best = -1e30f; int bi = 0;
                for (int g = 0; g < kG; ++g)
                    if (!gkeep[g] && gsc[g] > best) { best = gsc[g]; bi = g; }
                gkeep[bi] = true;
            }
            bool taken[kE];
            for (int i = 0; i < kE; ++i) taken[i] = false;
            int sel[kK]; float selw[kK]; float wsum = 0.f;
            for (int it = 0; it < kK; ++it) {
                float best = -1e30f; int bi = 0;
                for (int i = 0; i < kE; ++i)
                    if (gkeep[i >> 2] && !taken[i] && sb[i] > best) { best = sb[i]; bi = i; }
                taken[bi] = true;
                sel[it] = bi; selw[it] = sc[bi]; wsum += sc[bi];
            }
            float scl = kScale / wsum;
            for (int it = 0; it < kK; ++it) {
                int ee = sel[it];
                int slot = atomicAdd(&cnt[ee], 1);
                if (slot < kCap) {
                    tok_of_slot[ee * kCap + slot] = tok;
                    wt_of_slot[ee * kCap + slot] = selw[it] * scl;
                    route_slot[tok * kK + it] = ee * kCap + slot;
                    route_w[tok * kK + it]   = selw[it] * scl;
                } else {
                    route_slot[tok * kK + it] = -1;
                    route_w[tok * kK + it]   = 0.f;
                }
            }
        }
        return;
    }

    // ================= prep_w path: [R][C] fp32 -> [C][R] bf16, 64n x 128k tiles =================
    u16 (*Tl)[4104] = (u16(*)[4104])smem;
    int orig = blockIdx.x - ntok;               // 0..24575
    int wg = (orig & 7) * 3072 + (orig >> 3);   // bijective XCD chunking
    int group = wg >> 8;                        // 0..95 = (e, ty)
    int tile  = wg & 255;
    int ty = group % 3;
    int e  = group / 3;
    int R = (ty == 2) ? kI : kH;
    int C = (ty == 2) ? kH : kI;
    const float* src = (ty == 0) ? w1 : (ty == 1) ? w3 : w2;
    u16* dst = (ty == 0) ? w1t : (ty == 1) ? w3t : w2t;

    int ctiles = C >> 6;
    int n0 = (tile % ctiles) * 64;
    int k0 = (tile / ctiles) * 128;

    const float* se = src + (size_t)e * R * C;
    u16* de = dst + (size_t)e * R * C;

    int bn = (t & 15) * 4, bk = (t >> 4) * 4;
    #pragma unroll
    for (int sub = 0; sub < 2; ++sub) {
        const float* p = se + (size_t)(k0 + sub * 64 + bk) * C + n0 + bn;
        float4 c0 = *(const float4*)p;
        float4 c1 = *(const float4*)(p + C);
        float4 c2 = *(const float4*)(p + 2 * C);
        float4 c3 = *(const float4*)(p + 3 * C);
        u16* T = Tl[sub];
        uint2 q;
        q.x = pk2(c0.x, c1.x); q.y = pk2(c2.x, c3.x); *(uint2*)&T[swz(bn + 0, bk)] = q;
        q.x = pk2(c0.y, c1.y); q.y = pk2(c2.y, c3.y); *(uint2*)&T[swz(bn + 1, bk)] = q;
        q.x = pk2(c0.z, c1.z); q.y = pk2(c2.z, c3.z); *(uint2*)&T[swz(bn + 2, bk)] = q;
        q.x = pk2(c0.w, c1.w); q.y = pk2(c2.w, c3.w); *(uint2*)&T[swz(bn + 3, bk)] = q;
    }
    __syncthreads();
    #pragma unroll
    for (int it = 0; it < 4; ++it) {
        int f = it * 256 + t;
        int n = f >> 4, cc = f & 15;
        int sub = cc >> 3, kk = (cc & 7) * 8;
        uint4 v = *(const uint4*)&Tl[sub][swz(n, kk)];
        *(uint4*)(de + (size_t)(n0 + n) * R + k0 + sub * 64 + kk) = v;
    }
}

// ---------------- GEMM1: act = silu(xb@w1t^T)*(xb@w3t^T); R5 dbuf + XCD swizzle ----------------
__global__ __launch_bounds__(256, 2) void gemm1_kernel(
    const u16* __restrict__ xb, const u16* __restrict__ w1t, const u16* __restrict__ w3t,
    const int* __restrict__ tok_of_slot, const int* __restrict__ cnt,
    u16* __restrict__ act)
{
    int orig = blockIdx.x;
    int wg = (orig & 7) * 512 + (orig >> 3);
    int e = wg >> 7;
    int r = wg & 127;
    int m0 = (r >> 4) * 128;   // m-outer
    int n0 = (r & 15) * 64;    // n-inner

    int count = cnt[e];
    if (m0 >= count) return;

    __shared__ u16 sh[2][16384];

    int t = threadIdx.x;
    int oct = t & 7;
    int wb = (t >> 6) * 512;

    const u16* srcA[4];
    #pragma unroll
    for (int rr = 0; rr < 4; ++rr) {
        int row = rr * 32 + (t >> 3);
        int grow = m0 + row;
        int tk = (grow < count) ? tok_of_slot[e * kCap + grow] : 0;
        tk = (tk >= 0 && tk < 65536) ? tk : 0;
        srcA[rr] = xb + (size_t)tk * kH + ((oct ^ s8(row)) << 3);
    }
    const u16 *srcB1[2], *srcB3[2];
    #pragma unroll
    for (int rr = 0; rr < 2; ++rr) {
        int row = rr * 32 + (t >> 3);
        size_t go = (size_t)(n0 + row) * kH + ((oct ^ s8(row)) << 3);
        srcB1[rr] = w1t + (size_t)e * kH * kI + go;
        srcB3[rr] = w3t + (size_t)e * kH * kI + go;
    }

    auto stage = [&](int b, int k0) {
        u16* D = sh[b];
        #pragma unroll
        for (int rr = 0; rr < 4; ++rr)
            gload16(srcA[rr] + k0, D + rr * 2048 + wb);
        #pragma unroll
        for (int rr = 0; rr < 2; ++rr) {
            gload16(srcB1[rr] + k0, D + 8192 + rr * 2048 + wb);
            gload16(srcB3[rr] + k0, D + 12288 + rr * 2048 + wb);
        }
    };

    int lane = t & 63;
    int wv = t >> 6;
    int wm = (wv >> 1) * 64;
    int wn = (wv & 1) * 32;
    int lr = lane & 15;
    int kg = lane >> 4;

    f32x4 accg[4][2], accu[4][2];
    #pragma unroll
    for (int i = 0; i < 4; ++i)
        #pragma unroll
        for (int j = 0; j < 2; ++j) {
            accg[i][j] = f32x4{0.f, 0.f, 0.f, 0.f};
            accu[i][j] = f32x4{0.f, 0.f, 0.f, 0.f};
        }

    stage(0, 0);
    __syncthreads();
    int buf = 0;
    constexpr int NT = kH / 64;
    for (int kt = 0; kt < NT; ++kt) {
        if (kt + 1 < NT) stage(buf ^ 1, (kt + 1) * 64);
        const u16* As  = &sh[buf][0];
        const u16* B1s = &sh[buf][8192];
        const u16* B3s = &sh[buf][12288];
        #pragma unroll
        for (int h = 0; h < 2; ++h) {
            int kk = h * 32 + kg * 8;
            bf16x8 a[4];
            #pragma unroll
            for (int i = 0; i < 4; ++i)
                a[i] = *(const bf16x8*)&As[swz(wm + i * 16 + lr, kk)];
            #pragma unroll
            for (int ni = 0; ni < 2; ++ni) {
                bf16x8 b1 = *(const bf16x8*)&B1s[swz(wn + ni * 16 + lr, kk)];
                bf16x8 b3 = *(const bf16x8*)&B3s[swz(wn + ni * 16 + lr, kk)];
                #pragma unroll
                for (int mi = 0; mi < 4; ++mi) {
                    accg[mi][ni] = __builtin_amdgcn_mfma_f32_16x16x32_bf16(a[mi], b1, accg[mi][ni], 0, 0, 0);
                    accu[mi][ni] = __builtin_amdgcn_mfma_f32_16x16x32_bf16(a[mi], b3, accu[mi][ni], 0, 0, 0);
                }
            }
        }
        __syncthreads();
        buf ^= 1;
    }

    u16* actp = act + (size_t)e * kCap * kI;
    #pragma unroll
    for (int mi = 0; mi < 4; ++mi)
        #pragma unroll
        for (int ni = 0; ni < 2; ++ni)
            #pragma unroll
            for (int j = 0; j < 4; ++j) {
                int srow = m0 + wm + mi * 16 + kg * 4 + j;
                int icol = n0 + wn + ni * 16 + lr;
                float g = accg[mi][ni][j], u = accu[mi][ni][j];
                float sg = g / (1.f + __expf(-g));
                actp[(size_t)srow * kI + icol] = f2bf(sg * u);
            }
}

// ---------------- GEMM2: y = act @ w2t^T (bf16 y, no atomics); R5 dbuf + XCD swizzle ----------------
__global__ __launch_bounds__(256, 2) void gemm2_kernel(
    const u16* __restrict__ act, const u16* __restrict__ w2t,
    const int* __restrict__ cnt, u16* __restrict__ y)
{
    int orig = blockIdx.x;
    int wg = (orig & 7) * 512 + (orig >> 3);
    int e = wg >> 7;
    int r = wg & 127;
    int m0 = (r >> 4) * 128;   // m-outer
    int n0 = (r & 15) * 128;   // n-inner

    int count = cnt[e];
    if (m0 >= count) return;

    __shared__ u16 sh[2][16384];

    int t = threadIdx.x;
    int oct = t & 7;
    int wb = (t >> 6) * 512;

    const u16* srcA[4];
    const u16* srcB[4];
    {
        const u16* ae  = act + (size_t)e * kCap * kI;
        const u16* w2e = w2t + (size_t)e * kI * kH;
        #pragma unroll
        for (int rr = 0; rr < 4; ++rr) {
            int row = rr * 32 + (t >> 3);
            srcA[rr] = ae  + (size_t)(m0 + row) * kI + ((oct ^ s8(row)) << 3);
            srcB[rr] = w2e + (size_t)(n0 + row) * kI + ((oct ^ s8(row)) << 3);
        }
    }

    auto stage = [&](int b, int k0) {
        u16* D = sh[b];
        #pragma unroll
        for (int rr = 0; rr < 4; ++rr) {
            gload16(srcA[rr] + k0, D + rr * 2048 + wb);
            gload16(srcB[rr] + k0, D + 8192 + rr * 2048 + wb);
        }
    };

    int lane = t & 63;
    int wv = t >> 6;
    int wm = (wv >> 1) * 64;
    int wn = (wv & 1) * 64;
    int lr = lane & 15;
    int kg = lane >> 4;

    f32x4 acc[4][4];
    #pragma unroll
    for (int i = 0; i < 4; ++i)
        #pragma unroll
        for (int j = 0; j < 4; ++j) acc[i][j] = f32x4{0.f, 0.f, 0.f, 0.f};

    stage(0, 0);
    __syncthreads();
    int buf = 0;
    constexpr int NT = kI / 64;
    for (int kt = 0; kt < NT; ++kt) {
        if (kt + 1 < NT) stage(buf ^ 1, (kt + 1) * 64);
        const u16* As = &sh[buf][0];
        const u16* Bs = &sh[buf][8192];
        #pragma unroll
        for (int h = 0; h < 2; ++h) {
            int kk = h * 32 + kg * 8;
            bf16x8 a[4];
            #pragma unroll
            for (int i = 0; i < 4; ++i)
                a[i] = *(const bf16x8*)&As[swz(wm + i * 16 + lr, kk)];
            #pragma unroll
            for (int ni = 0; ni < 4; ++ni) {
                bf16x8 b = *(const bf16x8*)&Bs[swz(wn + ni * 16 + lr, kk)];
                #pragma unroll
                for (int mi = 0; mi < 4; ++mi)
                    acc[mi][ni] = __builtin_amdgcn_mfma_f32_16x16x32_bf16(a[mi], b, acc[mi][ni], 0, 0, 0);
            }
        }
        __syncthreads();
        buf ^= 1;
    }

    u16* ye = y + (size_t)e * kCap * kH;
    #pragma unroll
    for (int mi = 0; mi < 4; ++mi)
        #pragma unroll
        for (int j = 0; j < 4; ++j) {
            int sr = wm + mi * 16 + kg * 4 + j;
            if (m0 + sr < count) {
                #pragma unroll
                for (int ni = 0; ni < 4; ++ni)
                    ye[(size_t)(m0 + sr) * kH + n0 + wn + ni * 16 + lr] = f2bf(acc[mi][ni][j]);
            }
        }
}

// ---------------- combine: out[tok] = sum_k route_w * y[route_slot] ----------------
__global__ __launch_bounds__(256) void combine_kernel(
    const u16* __restrict__ y, const int* __restrict__ route_slot,
    const float* __restrict__ route_w, float* __restrict__ out)
{
    int tok = blockIdx.x;
    int t = threadIdx.x;
    int col = t * 8;

    int rs[kK]; float rw[kK];
    #pragma unroll
    for (int k = 0; k < kK; ++k) {
        rs[k] = route_slot[tok * kK + k];
        rw[k] = route_w[tok * kK + k];
    }

    float acc[8];
    #pragma unroll
    for (int j = 0; j < 8; ++j) acc[j] = 0.f;

    #pragma unroll
    for (int k = 0; k < kK; ++k) {
        if (rs[k] < 0) continue;
        uint4 v = *(const uint4*)(y + (size_t)rs[k] * kH + col);
        const u16* h = (const u16*)&v;
        float w = rw[k];
        #pragma unroll
        for (int j = 0; j < 8; ++j) acc[j] += w * bf2f(h[j]);
    }
    float4 o0 = make_float4(acc[0], acc[1], acc[2], acc[3]);
    float4 o1 = make_float4(acc[4], acc[5], acc[6], acc[7]);
    *(float4*)(out + (size_t)tok * kH + col) = o0;
    *(float4*)(out + (size_t)tok * kH + col + 4) = o1;
}

// ================= legacy fp32-staging kernels (fallback if ws too small) =================
__global__ __launch_bounds__(256, 3) void gemm1_legacy(
    const float* __restrict__ x, const float* __restrict__ w1g, const float* __restrict__ w3g,
    const int* __restrict__ tok_of_slot, const int* __restrict__ cnt,
    u16* __restrict__ act)
{
    int e = blockIdx.z;
    int count = cnt[e];
    int m0 = blockIdx.y * 128;
    if (m0 >= count) return;
    int n0 = blockIdx.x * 64;

    __shared__ u16 As[128 * 64];
    __shared__ u16 B1s[64 * 64];
    __shared__ u16 B3s[64 * 64];
    __shared__ int toks[128];

    int t = threadIdx.x;
    if (t < 128) {
        int s = m0 + t;
        toks[t] = (s < count) ? tok_of_slot[e * kCap + s] : -1;
    }
    __syncthreads();
    int lane = t & 63, wv = t >> 6;
    int wm = (wv >> 1) * 64, wn = (wv & 1) * 32;
    int lr = lane & 15, kg = lane >> 4;

    f32x4 accg[4][2], accu[4][2];
    #pragma unroll
    for (int i = 0; i < 4; ++i)
        #pragma unroll
        for (int j = 0; j < 2; ++j) {
            accg[i][j] = f32x4{0.f, 0.f, 0.f, 0.f};
            accu[i][j] = f32x4{0.f, 0.f, 0.f, 0.f};
        }
    const float* w1e = w1g + (size_t)e * kH * kI;
    const float* w3e = w3g + (size_t)e * kH * kI;

    for (int k0 = 0; k0 < kH; k0 += 64) {
        __syncthreads();
        #pragma unroll
        for (int r = 0; r < 4; ++r) {
            int f = r * 256 + t;
            int row = f >> 3, k8 = (f & 7) * 8;
            int tk = toks[row];
            float4 v0 = make_float4(0.f, 0.f, 0.f, 0.f), v1 = v0;
            if (tk >= 0) {
                const float* p = x + (size_t)tk * kH + k0 + k8;
                v0 = *(const float4*)p; v1 = *(const float4*)(p + 4);
            }
            uint4 w;
            w.x = pk2(v0.x, v0.y); w.y = pk2(v0.z, v0.w);
            w.z = pk2(v1.x, v1.y); w.w = pk2(v1.z, v1.w);
            *(uint4*)&As[swz(row, k8)] = w;
        }
        {
            int bn = (t & 15) * 4, bk = (t >> 4) * 4;
            const float* p1 = w1e + (size_t)(k0 + bk) * kI + n0 + bn;
            float4 c0 = *(const float4*)p1, c1 = *(const float4*)(p1 + kI),
                   c2 = *(const float4*)(p1 + 2 * kI), c3 = *(const float4*)(p1 + 3 * kI);
            uint2 q;
            q.x = pk2(c0.x, c1.x); q.y = pk2(c2.x, c3.x); *(uint2*)&B1s[swz(bn + 0, bk)] = q;
            q.x = pk2(c0.y, c1.y); q.y = pk2(c2.y, c3.y); *(uint2*)&B1s[swz(bn + 1, bk)] = q;
            q.x = pk2(c0.z, c1.z); q.y = pk2(c2.z, c3.z); *(uint2*)&B1s[swz(bn + 2, bk)] = q;
            q.x = pk2(c0.w, c1.w); q.y = pk2(c2.w, c3.w); *(uint2*)&B1s[swz(bn + 3, bk)] = q;
            const float* p3 = w3e + (size_t)(k0 + bk) * kI + n0 + bn;
            c0 = *(const float4*)p3; c1 = *(const float4*)(p3 + kI);
            c2 = *(const float4*)(p3 + 2 * kI); c3 = *(const float4*)(p3 + 3 * kI);
            q.x = pk2(c0.x, c1.x); q.y = pk2(c2.x, c3.x); *(uint2*)&B3s[swz(bn + 0, bk)] = q;
            q.x = pk2(c0.y, c1.y); q.y = pk2(c2.y, c3.y); *(uint2*)&B3s[swz(bn + 1, bk)] = q;
            q.x = pk2(c0.z, c1.z); q.y = pk2(c2.z, c3.z); *(uint2*)&B3s[swz(bn + 2, bk)] = q;
            q.x = pk2(c0.w, c1.w); q.y = pk2(c2.w, c3.w); *(uint2*)&B3s[swz(bn + 3, bk)] = q;
        }
        __syncthreads();
        #pragma unroll
        for (int h = 0; h < 2; ++h) {
            int kk = h * 32 + kg * 8;
            bf16x8 a[4];
            #pragma unroll
            for (int i = 0; i < 4; ++i)
                a[i] = *(const bf16x8*)&As[swz(wm + i * 16 + lr, kk)];
            #pragma unroll
            for (int ni = 0; ni < 2; ++ni) {
                bf16x8 b1 = *(const bf16x8*)&B1s[swz(wn + ni * 16 + lr, kk)];
                bf16x8 b3 = *(const bf16x8*)&B3s[swz(wn + ni * 16 + lr, kk)];
                #pragma unroll
                for (int mi = 0; mi < 4; ++mi) {
                    accg[mi][ni] = __builtin_amdgcn_mfma_f32_16x16x32_bf16(a[mi], b1, accg[mi][ni], 0, 0, 0);
                    accu[mi][ni] = __builtin_amdgcn_mfma_f32_16x16x32_bf16(a[mi], b3, accu[mi][ni], 0, 0, 0);
                }
            }
        }
    }
    u16* actp = act + (size_t)e * kCap * kI;
    #pragma unroll
    for (int mi = 0; mi < 4; ++mi)
        #pragma unroll
        for (int ni = 0; ni < 2; ++ni)
            #pragma unroll
            for (int j = 0; j < 4; ++j) {
                int srow = m0 + wm + mi * 16 + kg * 4 + j;
                int icol = n0 + wn + ni * 16 + lr;
                float g = accg[mi][ni][j], u = accu[mi][ni][j];
                float sg = g / (1.f + __expf(-g));
                actp[(size_t)srow * kI + icol] = f2bf(sg * u);
            }
}

__global__ __launch_bounds__(256, 3) void gemm2_legacy(
    const u16* __restrict__ act, const float* __restrict__ w2g,
    const int* __restrict__ tok_of_slot, const float* __restrict__ wt_of_slot,
    const int* __restrict__ cnt, float* __restrict__ out)
{
    int e = blockIdx.z;
    int count = cnt[e];
    int m0 = blockIdx.y * 128;
    if (m0 >= count) return;
    int n0 = blockIdx.x * 128;

    __shared__ u16 As[128 * 64];
    __shared__ u16 Bs[128 * 64];
    __shared__ int toks[128];
    __shared__ float wts[128];

    int t = threadIdx.x;
    if (t < 128) {
        int s = m0 + t;
        toks[t] = (s < count) ? tok_of_slot[e * kCap + s] : 0;
        wts[t]  = (s < count) ? wt_of_slot[e * kCap + s] : 0.f;
    }
    __syncthreads();
    int lane = t & 63, wv = t >> 6;
    int wm = (wv >> 1) * 64, wn = (wv & 1) * 64;
    int lr = lane & 15, kg = lane >> 4;

    f32x4 acc[4][4];
    #pragma unroll
    for (int i = 0; i < 4; ++i)
        #pragma unroll
        for (int j = 0; j < 4; ++j) acc[i][j] = f32x4{0.f, 0.f, 0.f, 0.f};

    const u16* ae = act + (size_t)e * kCap * kI;
    const float* w2e = w2g + (size_t)e * kI * kH;

    for (int k0 = 0; k0 < kI; k0 += 64) {
        __syncthreads();
        #pragma unroll
        for (int r = 0; r < 4; ++r) {
            int f = r * 256 + t;
            int row = f >> 3, k8 = (f & 7) * 8;
            uint4 v = *(const uint4*)(ae + (size_t)(m0 + row) * kI + k0 + k8);
            *(uint4*)&As[swz(row, k8)] = v;
        }
        #pragma unroll
        for (int r = 0; r < 2; ++r) {
            int f = r * 256 + t;
            int bn = (f & 31) * 4, bk = (f >> 5) * 4;
            const float* p = w2e + (size_t)(k0 + bk) * kH + n0 + bn;
            float4 c0 = *(const float4*)p, c1 = *(const float4*)(p + kH),
                   c2 = *(const float4*)(p + 2 * kH), c3 = *(const float4*)(p + 3 * kH);
            uint2 q;
            q.x = pk2(c0.x, c1.x); q.y = pk2(c2.x, c3.x); *(uint2*)&Bs[swz(bn + 0, bk)] = q;
            q.x = pk2(c0.y, c1.y); q.y = pk2(c2.y, c3.y); *(uint2*)&Bs[swz(bn + 1, bk)] = q;
            q.x = pk2(c0.z, c1.z); q.y = pk2(c2.z, c3.z); *(uint2*)&Bs[swz(bn + 2, bk)] = q;
            q.x = pk2(c0.w, c1.w); q.y = pk2(c2.w, c3.w); *(uint2*)&Bs[swz(bn + 3, bk)] = q;
        }
        __syncthreads();
        #pragma unroll
        for (int h = 0; h < 2; ++h) {
            int kk = h * 32 + kg * 8;
            bf16x8 a[4];
            #pragma unroll
            for (int i = 0; i < 4; ++i)
                a[i] = *(const bf16x8*)&As[swz(wm + i * 16 + lr, kk)];
            #pragma unroll
            for (int ni = 0; ni < 4; ++ni) {
                bf16x8 b = *(const bf16x8*)&Bs[swz(wn + ni * 16 + lr, kk)];
                #pragma unroll
                for (int mi = 0; mi < 4; ++mi)
                    acc[mi][ni] = __builtin_amdgcn_mfma_f32_16x16x32_bf16(a[mi], b, acc[mi][ni], 0, 0, 0);
            }
        }
    }
    #pragma unroll
    for (int mi = 0; mi < 4; ++mi)
        #pragma unroll
        for (int ni = 0; ni < 4; ++ni)
            #pragma unroll
            for (int j = 0; j < 4; ++j) {
                int sr = wm + mi * 16 + kg * 4 + j;
                if (m0 + sr < count) {
                    atomicAdd(&out[(size_t)toks[sr] * kH + n0 + wn + ni * 16 + lr],
                              wts[sr] * acc[mi][ni][j]);
                }
            }
}

extern "C" void kernel_launch(void* const* d_in, const int* in_sizes, int n_in,
                              void* d_out, int out_size, void* d_ws, size_t ws_size,
                              hipStream_t stream) {
    const float* x      = (const float*)d_in[0];
    const float* w_gate = (const float*)d_in[1];
    const float* gbias  = (const float*)d_in[2];
    const float* w1     = (const float*)d_in[3];
    const float* w3     = (const float*)d_in[4];
    const float* w2     = (const float*)d_in[5];
    float* out = (float*)d_out;

    int ntok = in_sizes[0] / kH;

    char* ws = (char*)d_ws;
    size_t off = 0;
    int*   cnt         = (int*)(ws + off);   off += 4096;
    int*   tok_of_slot = (int*)(ws + off);   off += (size_t)kE * kCap * 4;
    float* wt_of_slot  = (float*)(ws + off); off += (size_t)kE * kCap * 4;
    int*   route_slot  = (int*)(ws + off);   off += (size_t)ntok * kK * 4;
    float* route_w     = (float*)(ws + off); off += (size_t)ntok * kK * 4;
    u16*   act         = (u16*)(ws + off);   off += (size_t)kE * kCap * kI * 2;  // 64 MB
    u16*   xb  = (u16*)(ws + off); off += (size_t)ntok * kH * 2;                 // 8 MB
    u16*   w1t = (u16*)(ws + off); off += (size_t)kE * kH * kI * 2;              // 128 MB
    u16*   w3t = (u16*)(ws + off); off += (size_t)kE * kH * kI * 2;              // 128 MB
    u16*   w2t = (u16*)(ws + off); off += (size_t)kE * kI * kH * 2;              // 128 MB
    u16*   y   = w1t;   // y[E][kCap][kH] bf16 = 128 MB, aliases w1t (dead after gemm1)

    bool fast = (ws_size >= off);

    hipMemsetAsync(cnt, 0, kE * sizeof(int), stream);

    if (fast) {
        // fused gate + prep_w + prep_x (gate blocks first, hide under prep wave)
        prep_gate_kernel<<<ntok + kPrepBlocks, 256, 0, stream>>>(
            x, w_gate, gbias, cnt, tok_of_slot, wt_of_slot, route_slot, route_w, xb,
            w1, w3, w2, w1t, w3t, w2t, ntok);
        gemm1_kernel<<<4096, 256, 0, stream>>>(xb, w1t, w3t, tok_of_slot, cnt, act);
        gemm2_kernel<<<4096, 256, 0, stream>>>(act, w2t, cnt, y);
        combine_kernel<<<ntok, 256, 0, stream>>>(y, route_slot, route_w, out);
    } else {
        // gate-only (prep blocks absent); then legacy fused-conversion GEMMs
        prep_gate_kernel<<<ntok, 256, 0, stream>>>(
            x, w_gate, gbias, cnt, tok_of_slot, wt_of_slot, route_slot, route_w, nullptr,
            w1, w3, w2, nullptr, nullptr, nullptr, ntok);
        hipMemsetAsync(d_out, 0, (size_t)out_size * sizeof(float), stream);
        dim3 g1(kI / 64, kCap / 128, kE);
        gemm1_legacy<<<g1, 256, 0, stream>>>(x, w1, w3, tok_of_slot, cnt, act);
        dim3 g2(kH / 128, kCap / 128, kE);
        gemm2_legacy<<<g2, 256, 0, stream>>>(act, w2, tok_of_slot, wt_of_slot, cnt, out);
    }
}

// Round 14
// 616.951 us; speedup vs baseline: 1.1560x; 1.0196x over previous
//
#include <hip/hip_runtime.h>

typedef __attribute__((ext_vector_type(8))) short bf16x8;
typedef __attribute__((ext_vector_type(4))) float f32x4;
typedef unsigned short u16;
typedef unsigned int u32;

constexpr int kH   = 2048;   // hidden
constexpr int kI   = 1024;   // intermediate
constexpr int kE   = 32;     // experts
constexpr int kK   = 8;      // experts per token
constexpr int kG   = 8;      // groups
constexpr int kKG  = 4;      // groups kept
constexpr int kCap = 1024;   // capacity
constexpr float kScale = 2.5f;
constexpr int kPrep13Blocks = 16384;  // w1,w3: 64 (e,ty) groups x 256 tiles
constexpr int kPrep2Blocks  = 8192;   // w2: 32 experts x 256 tiles
constexpr int kGemmBlocks   = 4096;

__device__ __forceinline__ u16 f2bf(float f) {
    union { float f; u32 u; } v; v.f = f;
    u32 u = v.u + 0x7FFFu + ((v.u >> 16) & 1u);  // RNE
    return (u16)(u >> 16);
}
__device__ __forceinline__ float bf2f(u16 b) {
    union { u32 u; float f; } v; v.u = (u32)b << 16; return v.f;
}
__device__ __forceinline__ u32 pk2(float a, float b) {
    return (u32)f2bf(a) | ((u32)f2bf(b) << 16);
}

// ---- 64-elem-row (128B) swizzle ----
__device__ __forceinline__ int swz(int row, int k) {
    return row * 64 + (k ^ ((((row >> 3) ^ row) & 7) << 3));
}
__device__ __forceinline__ int s8(int row) { return ((row >> 3) ^ row) & 7; }

// async global->LDS, 16B per lane; LDS dest wave-uniform (HW adds lane*16B)
__device__ __forceinline__ void gload16(const void* g, void* l) {
    __builtin_amdgcn_global_load_lds(
        (const __attribute__((address_space(1))) unsigned int*)g,
        (__attribute__((address_space(3))) unsigned int*)l, 16, 0, 0);
}

// shared 64x128 fp32->bf16 transpose tile body (prep path)
__device__ __forceinline__ void prep_tile(
    const float* __restrict__ se, u16* __restrict__ de, int R, int C, int n0, int k0,
    u16 (*Tl)[4104], int t)
{
    int bn = (t & 15) * 4, bk = (t >> 4) * 4;
    #pragma unroll
    for (int sub = 0; sub < 2; ++sub) {
        const float* p = se + (size_t)(k0 + sub * 64 + bk) * C + n0 + bn;
        float4 c0 = *(const float4*)p;
        float4 c1 = *(const float4*)(p + C);
        float4 c2 = *(const float4*)(p + 2 * C);
        float4 c3 = *(const float4*)(p + 3 * C);
        u16* T = Tl[sub];
        uint2 q;
        q.x = pk2(c0.x, c1.x); q.y = pk2(c2.x, c3.x); *(uint2*)&T[swz(bn + 0, bk)] = q;
        q.x = pk2(c0.y, c1.y); q.y = pk2(c2.y, c3.y); *(uint2*)&T[swz(bn + 1, bk)] = q;
        q.x = pk2(c0.z, c1.z); q.y = pk2(c2.z, c3.z); *(uint2*)&T[swz(bn + 2, bk)] = q;
        q.x = pk2(c0.w, c1.w); q.y = pk2(c2.w, c3.w); *(uint2*)&T[swz(bn + 3, bk)] = q;
    }
    __syncthreads();
    #pragma unroll
    for (int it = 0; it < 4; ++it) {
        int f = it * 256 + t;
        int n = f >> 4, cc = f & 15;
        int sub = cc >> 3, kk = (cc & 7) * 8;
        uint4 v = *(const uint4*)&Tl[sub][swz(n, kk)];
        *(uint4*)(de + (size_t)(n0 + n) * R + k0 + sub * 64 + kk) = v;
    }
}

// ---------------- fused prep_gate: gate blocks [0,ntok) + w1/w3 prep blocks ----------------
__global__ __launch_bounds__(256) void prep_gate_kernel(
    const float* __restrict__ x, const float* __restrict__ w_gate,
    const float* __restrict__ gbias,
    int* __restrict__ cnt, int* __restrict__ tok_of_slot, float* __restrict__ wt_of_slot,
    int* __restrict__ route_slot, float* __restrict__ route_w, u16* __restrict__ xb,
    const float* __restrict__ w1, const float* __restrict__ w3,
    u16* __restrict__ w1t, u16* __restrict__ w3t, int ntok)
{
    __shared__ __align__(16) char smem[2 * 4104 * 2];   // 16.4 KB union
    int t = threadIdx.x;

    if ((int)blockIdx.x < ntok) {
        // ================= gate path =================
        float* part = (float*)smem;
        float* sc   = part + 256;
        float* sb   = sc + 32;
        int tok = blockIdx.x;
        const float* xr = x + (size_t)tok * kH;

        if (xb) {   // fused x -> bf16
            const float* p = xr + t * 8;
            float4 a = *(const float4*)p;
            float4 b = *(const float4*)(p + 4);
            uint4 o;
            o.x = pk2(a.x, a.y); o.y = pk2(a.z, a.w);
            o.z = pk2(b.x, b.y); o.w = pk2(b.z, b.w);
            *(uint4*)(xb + (size_t)tok * kH + t * 8) = o;
        }

        int e = t & 31, c = t >> 5;
        const float* wg = w_gate + e;
        float s = 0.f;
        #pragma unroll 4
        for (int h = c * 256; h < c * 256 + 256; ++h)
            s += xr[h] * wg[(size_t)h * kE];
        part[t] = s;
        __syncthreads();

        if (t < kE) {
            float logit = 0.f;
            #pragma unroll
            for (int cc = 0; cc < 8; ++cc) logit += part[t + 32 * cc];
            float sco = 1.f / (1.f + expf(-logit));
            sc[t] = sco;
            sb[t] = sco + gbias[t];
        }
        __syncthreads();

        if (t == 0) {
            float gsc[kG];
            for (int g = 0; g < kG; ++g) {
                float m1 = -1e30f, m2 = -1e30f;
                for (int j = 0; j < 4; ++j) {
                    float v = sb[g * 4 + j];
                    if (v > m1) { m2 = m1; m1 = v; } else if (v > m2) { m2 = v; }
                }
                gsc[g] = m1 + m2;
            }
            bool gkeep[kG];
            for (int g = 0; g < kG; ++g) gkeep[g] = false;
            for (int it = 0; it < kKG; ++it) {
                float best = -1e30f; int bi = 0;
                for (int g = 0; g < kG; ++g)
                    if (!gkeep[g] && gsc[g] > best) { best = gsc[g]; bi = g; }
                gkeep[bi] = true;
            }
            bool taken[kE];
            for (int i = 0; i < kE; ++i) taken[i] = false;
            int sel[kK]; float selw[kK]; float wsum = 0.f;
            for (int it = 0; it < kK; ++it) {
                float best = -1e30f; int bi = 0;
                for (int i = 0; i < kE; ++i)
                    if (gkeep[i >> 2] && !taken[i] && sb[i] > best) { best = sb[i]; bi = i; }
                taken[bi] = true;
                sel[it] = bi; selw[it] = sc[bi]; wsum += sc[bi];
            }
            float scl = kScale / wsum;
            for (int it = 0; it < kK; ++it) {
                int ee = sel[it];
                int slot = atomicAdd(&cnt[ee], 1);
                if (slot < kCap) {
                    tok_of_slot[ee * kCap + slot] = tok;
                    wt_of_slot[ee * kCap + slot] = selw[it] * scl;
                    route_slot[tok * kK + it] = ee * kCap + slot;
                    route_w[tok * kK + it]   = selw[it] * scl;
                } else {
                    route_slot[tok * kK + it] = -1;
                    route_w[tok * kK + it]   = 0.f;
                }
            }
        }
        return;
    }

    // ================= w1/w3 prep path =================
    u16 (*Tl)[4104] = (u16(*)[4104])smem;
    int orig = blockIdx.x - ntok;               // 0..16383
    int wg = (orig & 7) * 2048 + (orig >> 3);   // bijective XCD chunking
    int group = wg >> 8;                        // 0..63 = (e, ty)
    int tile  = wg & 255;
    int ty = group & 1;
    int e  = group >> 1;
    const float* src = ty ? w3 : w1;
    u16* dst = ty ? w3t : w1t;

    int n0 = (tile & 15) * 64;     // C = kI, 16 n-tiles
    int k0 = (tile >> 4) * 128;    // R = kH, 16 k-tiles

    prep_tile(src + (size_t)e * kH * kI, dst + (size_t)e * kH * kI,
              kH, kI, n0, k0, Tl, t);
}

// ---------------- GEMM1 (+fused w2 prep): blocks [0,4096) gemm, rest prep w2 ----------------
__global__ __launch_bounds__(256, 2) void gemm1_kernel(
    const u16* __restrict__ xb, const u16* __restrict__ w1t, const u16* __restrict__ w3t,
    const int* __restrict__ tok_of_slot, const int* __restrict__ cnt,
    u16* __restrict__ act,
    const float* __restrict__ w2, u16* __restrict__ w2t)
{
    __shared__ u16 sh[2][16384];   // gemm: 64KB dbuf; prep uses first 16.4KB
    int t = threadIdx.x;

    if ((int)blockIdx.x >= kGemmBlocks) {
        // ================= w2 prep path: [kI][kH] -> [kH][kI] =================
        u16 (*Tl)[4104] = (u16(*)[4104])&sh[0][0];
        int orig = blockIdx.x - kGemmBlocks;        // 0..8191
        int wg = (orig & 7) * 1024 + (orig >> 3);   // bijective XCD chunking
        int e  = wg >> 8;
        int tile = wg & 255;
        int n0 = (tile & 31) * 64;     // C = kH, 32 n-tiles
        int k0 = (tile >> 5) * 128;    // R = kI, 8 k-tiles
        prep_tile(w2 + (size_t)e * kI * kH, w2t + (size_t)e * kI * kH,
                  kI, kH, n0, k0, Tl, t);
        return;
    }

    int orig = blockIdx.x;
    int wg = (orig & 7) * 512 + (orig >> 3);
    int e = wg >> 7;
    int r = wg & 127;
    int m0 = (r >> 4) * 128;   // m-outer
    int n0 = (r & 15) * 64;    // n-inner

    int count = cnt[e];
    if (m0 >= count) return;

    int oct = t & 7;
    int wb = (t >> 6) * 512;

    const u16* srcA[4];
    #pragma unroll
    for (int rr = 0; rr < 4; ++rr) {
        int row = rr * 32 + (t >> 3);
        int grow = m0 + row;
        int tk = (grow < count) ? tok_of_slot[e * kCap + grow] : 0;
        tk = (tk >= 0 && tk < 65536) ? tk : 0;
        srcA[rr] = xb + (size_t)tk * kH + ((oct ^ s8(row)) << 3);
    }
    const u16 *srcB1[2], *srcB3[2];
    #pragma unroll
    for (int rr = 0; rr < 2; ++rr) {
        int row = rr * 32 + (t >> 3);
        size_t go = (size_t)(n0 + row) * kH + ((oct ^ s8(row)) << 3);
        srcB1[rr] = w1t + (size_t)e * kH * kI + go;
        srcB3[rr] = w3t + (size_t)e * kH * kI + go;
    }

    auto stage = [&](int b, int k0s) {
        u16* D = sh[b];
        #pragma unroll
        for (int rr = 0; rr < 4; ++rr)
            gload16(srcA[rr] + k0s, D + rr * 2048 + wb);
        #pragma unroll
        for (int rr = 0; rr < 2; ++rr) {
            gload16(srcB1[rr] + k0s, D + 8192 + rr * 2048 + wb);
            gload16(srcB3[rr] + k0s, D + 12288 + rr * 2048 + wb);
        }
    };

    int lane = t & 63;
    int wv = t >> 6;
    int wm = (wv >> 1) * 64;
    int wn = (wv & 1) * 32;
    int lr = lane & 15;
    int kg = lane >> 4;

    f32x4 accg[4][2], accu[4][2];
    #pragma unroll
    for (int i = 0; i < 4; ++i)
        #pragma unroll
        for (int j = 0; j < 2; ++j) {
            accg[i][j] = f32x4{0.f, 0.f, 0.f, 0.f};
            accu[i][j] = f32x4{0.f, 0.f, 0.f, 0.f};
        }

    stage(0, 0);
    __syncthreads();
    int buf = 0;
    constexpr int NT = kH / 64;
    for (int kt = 0; kt < NT; ++kt) {
        if (kt + 1 < NT) stage(buf ^ 1, (kt + 1) * 64);
        const u16* As  = &sh[buf][0];
        const u16* B1s = &sh[buf][8192];
        const u16* B3s = &sh[buf][12288];
        #pragma unroll
        for (int h = 0; h < 2; ++h) {
            int kk = h * 32 + kg * 8;
            bf16x8 a[4];
            #pragma unroll
            for (int i = 0; i < 4; ++i)
                a[i] = *(const bf16x8*)&As[swz(wm + i * 16 + lr, kk)];
            #pragma unroll
            for (int ni = 0; ni < 2; ++ni) {
                bf16x8 b1 = *(const bf16x8*)&B1s[swz(wn + ni * 16 + lr, kk)];
                bf16x8 b3 = *(const bf16x8*)&B3s[swz(wn + ni * 16 + lr, kk)];
                #pragma unroll
                for (int mi = 0; mi < 4; ++mi) {
                    accg[mi][ni] = __builtin_amdgcn_mfma_f32_16x16x32_bf16(a[mi], b1, accg[mi][ni], 0, 0, 0);
                    accu[mi][ni] = __builtin_amdgcn_mfma_f32_16x16x32_bf16(a[mi], b3, accu[mi][ni], 0, 0, 0);
                }
            }
        }
        __syncthreads();
        buf ^= 1;
    }

    u16* actp = act + (size_t)e * kCap * kI;
    #pragma unroll
    for (int mi = 0; mi < 4; ++mi)
        #pragma unroll
        for (int ni = 0; ni < 2; ++ni)
            #pragma unroll
            for (int j = 0; j < 4; ++j) {
                int srow = m0 + wm + mi * 16 + kg * 4 + j;
                int icol = n0 + wn + ni * 16 + lr;
                float g = accg[mi][ni][j], u = accu[mi][ni][j];
                float sg = g / (1.f + __expf(-g));
                actp[(size_t)srow * kI + icol] = f2bf(sg * u);
            }
}

// ---------------- GEMM2: y = act @ w2t^T (bf16 y, no atomics); R5 dbuf + XCD swizzle ----------------
__global__ __launch_bounds__(256, 2) void gemm2_kernel(
    const u16* __restrict__ act, const u16* __restrict__ w2t,
    const int* __restrict__ cnt, u16* __restrict__ y)
{
    int orig = blockIdx.x;
    int wg = (orig & 7) * 512 + (orig >> 3);
    int e = wg >> 7;
    int r = wg & 127;
    int m0 = (r >> 4) * 128;   // m-outer
    int n0 = (r & 15) * 128;   // n-inner

    int count = cnt[e];
    if (m0 >= count) return;

    __shared__ u16 sh[2][16384];

    int t = threadIdx.x;
    int oct = t & 7;
    int wb = (t >> 6) * 512;

    const u16* srcA[4];
    const u16* srcB[4];
    {
        const u16* ae  = act + (size_t)e * kCap * kI;
        const u16* w2e = w2t + (size_t)e * kI * kH;
        #pragma unroll
        for (int rr = 0; rr < 4; ++rr) {
            int row = rr * 32 + (t >> 3);
            srcA[rr] = ae  + (size_t)(m0 + row) * kI + ((oct ^ s8(row)) << 3);
            srcB[rr] = w2e + (size_t)(n0 + row) * kI + ((oct ^ s8(row)) << 3);
        }
    }

    auto stage = [&](int b, int k0) {
        u16* D = sh[b];
        #pragma unroll
        for (int rr = 0; rr < 4; ++rr) {
            gload16(srcA[rr] + k0, D + rr * 2048 + wb);
            gload16(srcB[rr] + k0, D + 8192 + rr * 2048 + wb);
        }
    };

    int lane = t & 63;
    int wv = t >> 6;
    int wm = (wv >> 1) * 64;
    int wn = (wv & 1) * 64;
    int lr = lane & 15;
    int kg = lane >> 4;

    f32x4 acc[4][4];
    #pragma unroll
    for (int i = 0; i < 4; ++i)
        #pragma unroll
        for (int j = 0; j < 4; ++j) acc[i][j] = f32x4{0.f, 0.f, 0.f, 0.f};

    stage(0, 0);
    __syncthreads();
    int buf = 0;
    constexpr int NT = kI / 64;
    for (int kt = 0; kt < NT; ++kt) {
        if (kt + 1 < NT) stage(buf ^ 1, (kt + 1) * 64);
        const u16* As = &sh[buf][0];
        const u16* Bs = &sh[buf][8192];
        #pragma unroll
        for (int h = 0; h < 2; ++h) {
            int kk = h * 32 + kg * 8;
            bf16x8 a[4];
            #pragma unroll
            for (int i = 0; i < 4; ++i)
                a[i] = *(const bf16x8*)&As[swz(wm + i * 16 + lr, kk)];
            #pragma unroll
            for (int ni = 0; ni < 4; ++ni) {
                bf16x8 b = *(const bf16x8*)&Bs[swz(wn + ni * 16 + lr, kk)];
                #pragma unroll
                for (int mi = 0; mi < 4; ++mi)
                    acc[mi][ni] = __builtin_amdgcn_mfma_f32_16x16x32_bf16(a[mi], b, acc[mi][ni], 0, 0, 0);
            }
        }
        __syncthreads();
        buf ^= 1;
    }

    u16* ye = y + (size_t)e * kCap * kH;
    #pragma unroll
    for (int mi = 0; mi < 4; ++mi)
        #pragma unroll
        for (int j = 0; j < 4; ++j) {
            int sr = wm + mi * 16 + kg * 4 + j;
            if (m0 + sr < count) {
                #pragma unroll
                for (int ni = 0; ni < 4; ++ni)
                    ye[(size_t)(m0 + sr) * kH + n0 + wn + ni * 16 + lr] = f2bf(acc[mi][ni][j]);
            }
        }
}

// ---------------- combine: out[tok] = sum_k route_w * y[route_slot] ----------------
__global__ __launch_bounds__(256) void combine_kernel(
    const u16* __restrict__ y, const int* __restrict__ route_slot,
    const float* __restrict__ route_w, float* __restrict__ out)
{
    int tok = blockIdx.x;
    int t = threadIdx.x;
    int col = t * 8;

    int rs[kK]; float rw[kK];
    #pragma unroll
    for (int k = 0; k < kK; ++k) {
        rs[k] = route_slot[tok * kK + k];
        rw[k] = route_w[tok * kK + k];
    }

    float acc[8];
    #pragma unroll
    for (int j = 0; j < 8; ++j) acc[j] = 0.f;

    #pragma unroll
    for (int k = 0; k < kK; ++k) {
        if (rs[k] < 0) continue;
        uint4 v = *(const uint4*)(y + (size_t)rs[k] * kH + col);
        const u16* h = (const u16*)&v;
        float w = rw[k];
        #pragma unroll
        for (int j = 0; j < 8; ++j) acc[j] += w * bf2f(h[j]);
    }
    float4 o0 = make_float4(acc[0], acc[1], acc[2], acc[3]);
    float4 o1 = make_float4(acc[4], acc[5], acc[6], acc[7]);
    *(float4*)(out + (size_t)tok * kH + col) = o0;
    *(float4*)(out + (size_t)tok * kH + col + 4) = o1;
}

// ================= legacy fp32-staging kernels (fallback if ws too small) =================
__global__ __launch_bounds__(256, 3) void gemm1_legacy(
    const float* __restrict__ x, const float* __restrict__ w1g, const float* __restrict__ w3g,
    const int* __restrict__ tok_of_slot, const int* __restrict__ cnt,
    u16* __restrict__ act)
{
    int e = blockIdx.z;
    int count = cnt[e];
    int m0 = blockIdx.y * 128;
    if (m0 >= count) return;
    int n0 = blockIdx.x * 64;

    __shared__ u16 As[128 * 64];
    __shared__ u16 B1s[64 * 64];
    __shared__ u16 B3s[64 * 64];
    __shared__ int toks[128];

    int t = threadIdx.x;
    if (t < 128) {
        int s = m0 + t;
        toks[t] = (s < count) ? tok_of_slot[e * kCap + s] : -1;
    }
    __syncthreads();
    int lane = t & 63, wv = t >> 6;
    int wm = (wv >> 1) * 64, wn = (wv & 1) * 32;
    int lr = lane & 15, kg = lane >> 4;

    f32x4 accg[4][2], accu[4][2];
    #pragma unroll
    for (int i = 0; i < 4; ++i)
        #pragma unroll
        for (int j = 0; j < 2; ++j) {
            accg[i][j] = f32x4{0.f, 0.f, 0.f, 0.f};
            accu[i][j] = f32x4{0.f, 0.f, 0.f, 0.f};
        }
    const float* w1e = w1g + (size_t)e * kH * kI;
    const float* w3e = w3g + (size_t)e * kH * kI;

    for (int k0 = 0; k0 < kH; k0 += 64) {
        __syncthreads();
        #pragma unroll
        for (int r = 0; r < 4; ++r) {
            int f = r * 256 + t;
            int row = f >> 3, k8 = (f & 7) * 8;
            int tk = toks[row];
            float4 v0 = make_float4(0.f, 0.f, 0.f, 0.f), v1 = v0;
            if (tk >= 0) {
                const float* p = x + (size_t)tk * kH + k0 + k8;
                v0 = *(const float4*)p; v1 = *(const float4*)(p + 4);
            }
            uint4 w;
            w.x = pk2(v0.x, v0.y); w.y = pk2(v0.z, v0.w);
            w.z = pk2(v1.x, v1.y); w.w = pk2(v1.z, v1.w);
            *(uint4*)&As[swz(row, k8)] = w;
        }
        {
            int bn = (t & 15) * 4, bk = (t >> 4) * 4;
            const float* p1 = w1e + (size_t)(k0 + bk) * kI + n0 + bn;
            float4 c0 = *(const float4*)p1, c1 = *(const float4*)(p1 + kI),
                   c2 = *(const float4*)(p1 + 2 * kI), c3 = *(const float4*)(p1 + 3 * kI);
            uint2 q;
            q.x = pk2(c0.x, c1.x); q.y = pk2(c2.x, c3.x); *(uint2*)&B1s[swz(bn + 0, bk)] = q;
            q.x = pk2(c0.y, c1.y); q.y = pk2(c2.y, c3.y); *(uint2*)&B1s[swz(bn + 1, bk)] = q;
            q.x = pk2(c0.z, c1.z); q.y = pk2(c2.z, c3.z); *(uint2*)&B1s[swz(bn + 2, bk)] = q;
            q.x = pk2(c0.w, c1.w); q.y = pk2(c2.w, c3.w); *(uint2*)&B1s[swz(bn + 3, bk)] = q;
            const float* p3 = w3e + (size_t)(k0 + bk) * kI + n0 + bn;
            c0 = *(const float4*)p3; c1 = *(const float4*)(p3 + kI);
            c2 = *(const float4*)(p3 + 2 * kI); c3 = *(const float4*)(p3 + 3 * kI);
            q.x = pk2(c0.x, c1.x); q.y = pk2(c2.x, c3.x); *(uint2*)&B3s[swz(bn + 0, bk)] = q;
            q.x = pk2(c0.y, c1.y); q.y = pk2(c2.y, c3.y); *(uint2*)&B3s[swz(bn + 1, bk)] = q;
            q.x = pk2(c0.z, c1.z); q.y = pk2(c2.z, c3.z); *(uint2*)&B3s[swz(bn + 2, bk)] = q;
            q.x = pk2(c0.w, c1.w); q.y = pk2(c2.w, c3.w); *(uint2*)&B3s[swz(bn + 3, bk)] = q;
        }
        __syncthreads();
        #pragma unroll
        for (int h = 0; h < 2; ++h) {
            int kk = h * 32 + kg * 8;
            bf16x8 a[4];
            #pragma unroll
            for (int i = 0; i < 4; ++i)
                a[i] = *(const bf16x8*)&As[swz(wm + i * 16 + lr, kk)];
            #pragma unroll
            for (int ni = 0; ni < 2; ++ni) {
                bf16x8 b1 = *(const bf16x8*)&B1s[swz(wn + ni * 16 + lr, kk)];
                bf16x8 b3 = *(const bf16x8*)&B3s[swz(wn + ni * 16 + lr, kk)];
                #pragma unroll
                for (int mi = 0; mi < 4; ++mi) {
                    accg[mi][ni] = __builtin_amdgcn_mfma_f32_16x16x32_bf16(a[mi], b1, accg[mi][ni], 0, 0, 0);
                    accu[mi][ni] = __builtin_amdgcn_mfma_f32_16x16x32_bf16(a[mi], b3, accu[mi][ni], 0, 0, 0);
                }
            }
        }
    }
    u16* actp = act + (size_t)e * kCap * kI;
    #pragma unroll
    for (int mi = 0; mi < 4; ++mi)
        #pragma unroll
        for (int ni = 0; ni < 2; ++ni)
            #pragma unroll
            for (int j = 0; j < 4; ++j) {
                int srow = m0 + wm + mi * 16 + kg * 4 + j;
                int icol = n0 + wn + ni * 16 + lr;
                float g = accg[mi][ni][j], u = accu[mi][ni][j];
                float sg = g / (1.f + __expf(-g));
                actp[(size_t)srow * kI + icol] = f2bf(sg * u);
            }
}

__global__ __launch_bounds__(256, 3) void gemm2_legacy(
    const u16* __restrict__ act, const float* __restrict__ w2g,
    const int* __restrict__ tok_of_slot, const float* __restrict__ wt_of_slot,
    const int* __restrict__ cnt, float* __restrict__ out)
{
    int e = blockIdx.z;
    int count = cnt[e];
    int m0 = blockIdx.y * 128;
    if (m0 >= count) return;
    int n0 = blockIdx.x * 128;

    __shared__ u16 As[128 * 64];
    __shared__ u16 Bs[128 * 64];
    __shared__ int toks[128];
    __shared__ float wts[128];

    int t = threadIdx.x;
    if (t < 128) {
        int s = m0 + t;
        toks[t] = (s < count) ? tok_of_slot[e * kCap + s] : 0;
        wts[t]  = (s < count) ? wt_of_slot[e * kCap + s] : 0.f;
    }
    __syncthreads();
    int lane = t & 63, wv = t >> 6;
    int wm = (wv >> 1) * 64, wn = (wv & 1) * 64;
    int lr = lane & 15, kg = lane >> 4;

    f32x4 acc[4][4];
    #pragma unroll
    for (int i = 0; i < 4; ++i)
        #pragma unroll
        for (int j = 0; j < 4; ++j) acc[i][j] = f32x4{0.f, 0.f, 0.f, 0.f};

    const u16* ae = act + (size_t)e * kCap * kI;
    const float* w2e = w2g + (size_t)e * kI * kH;

    for (int k0 = 0; k0 < kI; k0 += 64) {
        __syncthreads();
        #pragma unroll
        for (int r = 0; r < 4; ++r) {
            int f = r * 256 + t;
            int row = f >> 3, k8 = (f & 7) * 8;
            uint4 v = *(const uint4*)(ae + (size_t)(m0 + row) * kI + k0 + k8);
            *(uint4*)&As[swz(row, k8)] = v;
        }
        #pragma unroll
        for (int r = 0; r < 2; ++r) {
            int f = r * 256 + t;
            int bn = (f & 31) * 4, bk = (f >> 5) * 4;
            const float* p = w2e + (size_t)(k0 + bk) * kH + n0 + bn;
            float4 c0 = *(const float4*)p, c1 = *(const float4*)(p + kH),
                   c2 = *(const float4*)(p + 2 * kH), c3 = *(const float4*)(p + 3 * kH);
            uint2 q;
            q.x = pk2(c0.x, c1.x); q.y = pk2(c2.x, c3.x); *(uint2*)&Bs[swz(bn + 0, bk)] = q;
            q.x = pk2(c0.y, c1.y); q.y = pk2(c2.y, c3.y); *(uint2*)&Bs[swz(bn + 1, bk)] = q;
            q.x = pk2(c0.z, c1.z); q.y = pk2(c2.z, c3.z); *(uint2*)&Bs[swz(bn + 2, bk)] = q;
            q.x = pk2(c0.w, c1.w); q.y = pk2(c2.w, c3.w); *(uint2*)&Bs[swz(bn + 3, bk)] = q;
        }
        __syncthreads();
        #pragma unroll
        for (int h = 0; h < 2; ++h) {
            int kk = h * 32 + kg * 8;
            bf16x8 a[4];
            #pragma unroll
            for (int i = 0; i < 4; ++i)
                a[i] = *(const bf16x8*)&As[swz(wm + i * 16 + lr, kk)];
            #pragma unroll
            for (int ni = 0; ni < 4; ++ni) {
                bf16x8 b = *(const bf16x8*)&Bs[swz(wn + ni * 16 + lr, kk)];
                #pragma unroll
                for (int mi = 0; mi < 4; ++mi)
                    acc[mi][ni] = __builtin_amdgcn_mfma_f32_16x16x32_bf16(a[mi], b, acc[mi][ni], 0, 0, 0);
            }
        }
    }
    #pragma unroll
    for (int mi = 0; mi < 4; ++mi)
        #pragma unroll
        for (int ni = 0; ni < 4; ++ni)
            #pragma unroll
            for (int j = 0; j < 4; ++j) {
                int sr = wm + mi * 16 + kg * 4 + j;
                if (m0 + sr < count) {
                    atomicAdd(&out[(size_t)toks[sr] * kH + n0 + wn + ni * 16 + lr],
                              wts[sr] * acc[mi][ni][j]);
                }
            }
}

extern "C" void kernel_launch(void* const* d_in, const int* in_sizes, int n_in,
                              void* d_out, int out_size, void* d_ws, size_t ws_size,
                              hipStream_t stream) {
    const float* x      = (const float*)d_in[0];
    const float* w_gate = (const float*)d_in[1];
    const float* gbias  = (const float*)d_in[2];
    const float* w1     = (const float*)d_in[3];
    const float* w3     = (const float*)d_in[4];
    const float* w2     = (const float*)d_in[5];
    float* out = (float*)d_out;

    int ntok = in_sizes[0] / kH;

    char* ws = (char*)d_ws;
    size_t off = 0;
    int*   cnt         = (int*)(ws + off);   off += 4096;
    int*   tok_of_slot = (int*)(ws + off);   off += (size_t)kE * kCap * 4;
    float* wt_of_slot  = (float*)(ws + off); off += (size_t)kE * kCap * 4;
    int*   route_slot  = (int*)(ws + off);   off += (size_t)ntok * kK * 4;
    float* route_w     = (float*)(ws + off); off += (size_t)ntok * kK * 4;
    u16*   act         = (u16*)(ws + off);   off += (size_t)kE * kCap * kI * 2;  // 64 MB
    u16*   xb  = (u16*)(ws + off); off += (size_t)ntok * kH * 2;                 // 8 MB
    u16*   w1t = (u16*)(ws + off); off += (size_t)kE * kH * kI * 2;              // 128 MB
    u16*   w3t = (u16*)(ws + off); off += (size_t)kE * kH * kI * 2;              // 128 MB
    u16*   w2t = (u16*)(ws + off); off += (size_t)kE * kI * kH * 2;              // 128 MB
    u16*   y   = w1t;   // y[E][kCap][kH] bf16 = 128 MB, aliases w1t (dead after gemm1)

    bool fast = (ws_size >= off);

    hipMemsetAsync(cnt, 0, kE * sizeof(int), stream);

    if (fast) {
        // fused gate + x-convert + w1/w3 prep
        prep_gate_kernel<<<ntok + kPrep13Blocks, 256, 0, stream>>>(
            x, w_gate, gbias, cnt, tok_of_slot, wt_of_slot, route_slot, route_w, xb,
            w1, w3, w1t, w3t, ntok);
        // gemm1 + fused w2 prep (w2t ready before gemm2 by stream order)
        gemm1_kernel<<<kGemmBlocks + kPrep2Blocks, 256, 0, stream>>>(
            xb, w1t, w3t, tok_of_slot, cnt, act, w2, w2t);
        gemm2_kernel<<<4096, 256, 0, stream>>>(act, w2t, cnt, y);
        combine_kernel<<<ntok, 256, 0, stream>>>(y, route_slot, route_w, out);
    } else {
        // gate-only (prep blocks absent); then legacy fused-conversion GEMMs
        prep_gate_kernel<<<ntok, 256, 0, stream>>>(
            x, w_gate, gbias, cnt, tok_of_slot, wt_of_slot, route_slot, route_w, nullptr,
            w1, w3, nullptr, nullptr, ntok);
        hipMemsetAsync(d_out, 0, (size_t)out_size * sizeof(float), stream);
        dim3 g1(kI / 64, kCap / 128, kE);
        gemm1_legacy<<<g1, 256, 0, stream>>>(x, w1, w3, tok_of_slot, cnt, act);
        dim3 g2(kH / 128, kCap / 128, kE);
        gemm2_legacy<<<g2, 256, 0, stream>>>(act, w2, tok_of_slot, wt_of_slot, cnt, out);
    }
}